// Round 2
// baseline (1192.488 us; speedup 1.0000x reference)
//
#include <hip/hip_runtime.h>
#include <cstdint>
#include <math.h>

#define EPS_BN 1e-5f
#define SLOPE 0.01f

// ---------- weight transform: w[O][I][3] -> wT[(i*3+t)*O + o] ----------
__global__ __launch_bounds__(256)
void wprep_kernel(const float* __restrict__ w, float* __restrict__ wT,
                  int CIN, int COUT)
{
    int total = CIN * 3 * COUT;
    for (int idx = blockIdx.x * 256 + threadIdx.x; idx < total;
         idx += gridDim.x * 256) {
        int o = idx % COUT;
        int r = idx / COUT;            // r = i*3 + t
        int i = r / 3, t = r - i * 3;
        wT[idx] = w[((size_t)o * CIN + i) * 3 + t];
    }
}

// ---------- fused conv1d(k=3,pad=1) + BN(eval) + LeakyReLU ----------
// tile: 64 out-channels x 64 out-positions per block, one batch.
// thread micro-tile: 4 oc x 4 pos. K staged in LDS in chunks of IC=16.
template<int CIN, int COUT, int LIN, int STRIDE, bool TRANS_OUT>
__global__ __launch_bounds__(256)
void conv_bn_lrelu(const float* __restrict__ in, const float* __restrict__ wT,
                   const float* __restrict__ bias,
                   const float* __restrict__ gg, const float* __restrict__ be,
                   const float* __restrict__ mm, const float* __restrict__ vv,
                   float* __restrict__ out)
{
    constexpr int LOUT  = LIN / STRIDE;
    constexpr int XSPAN = STRIDE * 63 + 3;       // 129 (s2) or 66 (s1)
    constexpr int XROW  = (XSPAN + 3) & ~3;      // 132 or 68 (16B-aligned rows)
    constexpr int IC    = 16;
    constexpr int NX    = 3 * STRIDE + 3;        // 9 or 6 x-values per thread

    __shared__ __align__(16) float xs[IC][XROW];
    __shared__ __align__(16) float wsh[IC * 3][64];

    const int tid = threadIdx.x;
    const int l0  = blockIdx.x * 64;
    const int o0  = blockIdx.y * 64;
    const int b   = blockIdx.z;

    const int lt = tid & 15, ot = tid >> 4;
    const int lb = lt * 4,   ob = ot * 4;

    float acc[4][4] = {};                        // [oo][ll]
    const int l0in = l0 * STRIDE - 1;
    const float* inb = in + (size_t)b * CIN * LIN;

    for (int i0 = 0; i0 < CIN; i0 += IC) {
        __syncthreads();
        // stage X chunk (with zero padding at the borders)
        for (int idx = tid; idx < IC * XSPAN; idx += 256) {
            int i = idx / XSPAN, j = idx - i * XSPAN;
            int p = l0in + j;
            float val = 0.0f;
            if (p >= 0 && p < LIN) val = inb[(size_t)(i0 + i) * LIN + p];
            xs[i][j] = val;
        }
        // stage W chunk: wsh[i*3+t][o] <- wT[(i0*3 + i*3+t)*COUT + o0+o]
        for (int idx = tid; idx < IC * 3 * 64; idx += 256) {
            int o = idx & 63, r = idx >> 6;
            wsh[r][o] = wT[(size_t)(i0 * 3 + r) * COUT + o0 + o];
        }
        __syncthreads();

        #pragma unroll
        for (int i = 0; i < IC; ++i) {
            float xr[NX];
            if (STRIDE == 2) {
                float4 a = *(const float4*)&xs[i][lb * 2];
                float4 c = *(const float4*)&xs[i][lb * 2 + 4];
                xr[0] = a.x; xr[1] = a.y; xr[2] = a.z; xr[3] = a.w;
                xr[4] = c.x; xr[5] = c.y; xr[6] = c.z; xr[7] = c.w;
                xr[8] = xs[i][lb * 2 + 8];
            } else {
                float4 a = *(const float4*)&xs[i][lb];
                xr[0] = a.x; xr[1] = a.y; xr[2] = a.z; xr[3] = a.w;
                xr[4] = xs[i][lb + 4];
                xr[5] = xs[i][lb + 5];
            }
            #pragma unroll
            for (int t = 0; t < 3; ++t) {
                float4 wv = *(const float4*)&wsh[i * 3 + t][ob];
                float wp[4] = {wv.x, wv.y, wv.z, wv.w};
                #pragma unroll
                for (int oo = 0; oo < 4; ++oo)
                    #pragma unroll
                    for (int ll = 0; ll < 4; ++ll)
                        acc[oo][ll] = fmaf(wp[oo], xr[ll * STRIDE + t], acc[oo][ll]);
            }
        }
    }

    // epilogue: +bias, BN (eval), LeakyReLU — same op order as reference
    float res[4][4];
    #pragma unroll
    for (int oo = 0; oo < 4; ++oo) {
        int o = o0 + ob + oo;
        float inv = 1.0f / sqrtf(vv[o] + EPS_BN);
        float sc  = gg[o] * inv;
        float mo = mm[o], beo = be[o], bo = bias[o];
        #pragma unroll
        for (int ll = 0; ll < 4; ++ll) {
            float y = acc[oo][ll] + bo;
            float t = (y - mo) * sc + beo;
            res[oo][ll] = t >= 0.0f ? t : SLOPE * t;
        }
    }
    if (!TRANS_OUT) {
        #pragma unroll
        for (int oo = 0; oo < 4; ++oo) {
            int o = o0 + ob + oo;
            float4 r4 = make_float4(res[oo][0], res[oo][1], res[oo][2], res[oo][3]);
            *(float4*)&out[((size_t)b * COUT + o) * LOUT + l0 + lb] = r4;
        }
    } else {
        // write transposed: f[(b*LOUT + l)*COUT + o]  (flat [N][D])
        #pragma unroll
        for (int ll = 0; ll < 4; ++ll) {
            int l = l0 + lb + ll;
            float4 r4 = make_float4(res[0][ll], res[1][ll], res[2][ll], res[3][ll]);
            *(float4*)&out[((size_t)(b * LOUT + l)) * COUT + o0 + ob] = r4;
        }
    }
}

// ---------- 32x32 LDS tile transpose: in[R][C] -> out[C][R] ----------
__global__ __launch_bounds__(256)
void transpose_kernel(const float* __restrict__ in, float* __restrict__ out,
                      int R, int C)
{
    __shared__ float t[32][33];
    int c0 = blockIdx.x * 32, r0 = blockIdx.y * 32;
    int x = threadIdx.x & 31, y = threadIdx.x >> 5;   // y in [0,8)
    #pragma unroll
    for (int k = 0; k < 4; ++k)
        t[y + k * 8][x] = in[(size_t)(r0 + y + k * 8) * C + c0 + x];
    __syncthreads();
    #pragma unroll
    for (int k = 0; k < 4; ++k)
        out[(size_t)(c0 + y + k * 8) * R + r0 + x] = t[x][y + k * 8];
}

// ---------- row sum-of-squares from transposed layout inT[D][N] ----------
__global__ __launch_bounds__(256)
void sumsq_kernel(const float* __restrict__ inT, float* __restrict__ outv,
                  int N, int D)
{
    int n = blockIdx.x * 256 + threadIdx.x;
    if (n >= N) return;
    float s = 0.0f;
    for (int d = 0; d < D; ++d) {
        float x = inT[(size_t)d * N + n];
        s = fmaf(x, x, s);
    }
    outv[n] = s;
}

// ---------- dist[n][k] = sf[n] + se[k] - 2 * <f_n, e_k> ----------
__global__ __launch_bounds__(256)
void dist_kernel(const float* __restrict__ fT, const float* __restrict__ eT,
                 const float* __restrict__ sf, const float* __restrict__ se,
                 float* __restrict__ dist)
{
    constexpr int N = 8192, K = 4096, D = 128;
    __shared__ __align__(16) float fs[D][64];
    __shared__ __align__(16) float es[D][64];
    const int tid = threadIdx.x;
    const int k0 = blockIdx.x * 64, n0 = blockIdx.y * 64;
    const int r = tid & 63, c0 = tid >> 6;

    for (int cc = 0; cc < 32; ++cc) {
        int d = c0 * 32 + cc;
        fs[d][r] = fT[(size_t)d * N + n0 + r];
        es[d][r] = eT[(size_t)d * K + k0 + r];
    }
    __syncthreads();

    const int nt = tid & 15, kt = tid >> 4;
    float acc[4][4] = {};
    #pragma unroll 4
    for (int d = 0; d < D; ++d) {
        float4 a  = *(const float4*)&fs[d][nt * 4];
        float4 bv = *(const float4*)&es[d][kt * 4];
        float ax[4] = {a.x, a.y, a.z, a.w};
        float bx[4] = {bv.x, bv.y, bv.z, bv.w};
        #pragma unroll
        for (int i = 0; i < 4; ++i)
            #pragma unroll
            for (int j = 0; j < 4; ++j)
                acc[i][j] = fmaf(ax[i], bx[j], acc[i][j]);
    }

    #pragma unroll
    for (int i = 0; i < 4; ++i) {
        int n = n0 + nt * 4 + i;
        float sfn = sf[n];
        float o0v = (sfn + se[k0 + kt * 4 + 0]) - 2.0f * acc[i][0];
        float o1v = (sfn + se[k0 + kt * 4 + 1]) - 2.0f * acc[i][1];
        float o2v = (sfn + se[k0 + kt * 4 + 2]) - 2.0f * acc[i][2];
        float o3v = (sfn + se[k0 + kt * 4 + 3]) - 2.0f * acc[i][3];
        float4 r4 = make_float4(o0v, o1v, o2v, o3v);
        *(float4*)&dist[(size_t)n * K + k0 + kt * 4] = r4;
    }
}

// ---------- argmin over each row of dist (first-index tie-break) ----------
__global__ __launch_bounds__(256)
void argmin_kernel(const float* __restrict__ dist, float* __restrict__ codes)
{
    constexpr int K = 4096;
    __shared__ float sv[256];
    __shared__ int   si[256];
    const int n = blockIdx.x;
    const float* row = dist + (size_t)n * K;
    float bv = 3.4e38f;
    int bi = 0;
    for (int k = threadIdx.x; k < K; k += 256) {
        float v = row[k];
        if (v < bv) { bv = v; bi = k; }   // ascending k => first occurrence kept
    }
    sv[threadIdx.x] = bv; si[threadIdx.x] = bi;
    __syncthreads();
    for (int s = 128; s > 0; s >>= 1) {
        if (threadIdx.x < s) {
            float v2 = sv[threadIdx.x + s]; int i2 = si[threadIdx.x + s];
            if (v2 < sv[threadIdx.x] ||
                (v2 == sv[threadIdx.x] && i2 < si[threadIdx.x])) {
                sv[threadIdx.x] = v2; si[threadIdx.x] = i2;
            }
        }
        __syncthreads();
    }
    if (threadIdx.x == 0) codes[n] = (float)si[0];
}

// ---------------------------------------------------------------
extern "C" void kernel_launch(void* const* d_in, const int* in_sizes, int n_in,
                              void* d_out, int out_size, void* d_ws, size_t ws_size,
                              hipStream_t stream)
{
    const float* x   = (const float*)d_in[0];
    const float* w1  = (const float*)d_in[1];
    const float* b1  = (const float*)d_in[2];
    const float* w2  = (const float*)d_in[3];
    const float* b2  = (const float*)d_in[4];
    const float* w3  = (const float*)d_in[5];
    const float* b3  = (const float*)d_in[6];
    const float* w4  = (const float*)d_in[7];
    const float* b4  = (const float*)d_in[8];
    const float* g1  = (const float*)d_in[9];
    const float* be1 = (const float*)d_in[10];
    const float* m1  = (const float*)d_in[11];
    const float* v1  = (const float*)d_in[12];
    const float* g2  = (const float*)d_in[13];
    const float* be2 = (const float*)d_in[14];
    const float* m2  = (const float*)d_in[15];
    const float* v2  = (const float*)d_in[16];
    const float* g3  = (const float*)d_in[17];
    const float* be3 = (const float*)d_in[18];
    const float* m3  = (const float*)d_in[19];
    const float* v3  = (const float*)d_in[20];
    const float* g4  = (const float*)d_in[21];
    const float* be4 = (const float*)d_in[22];
    const float* m4  = (const float*)d_in[23];
    const float* v4  = (const float*)d_in[24];
    const float* emb = (const float*)d_in[25];

    float* outf  = (float*)d_out;
    float* codes = outf;            // [8192] written as float
    float* dist  = outf + 8192;     // [8192][4096]

    // workspace layout (floats)
    float* ws  = (float*)d_ws;
    float* wT1 = ws;                  // 196608
    float* wT2 = ws + 196608;         // 393216
    float* wT3 = ws + 589824;         // 786432
    float* wT4 = ws + 1376256;        // 196608
    float* h3  = ws + 1572864;        // 4194304  [32][512][256]
    float* f   = ws + 5767168;        // 1048576  [8192][128]
    float* fT  = ws + 6815744;        // 1048576  [128][8192]
    float* eT  = ws + 7864320;        // 524288   [128][4096]
    float* sf  = ws + 8388608;        // 8192
    float* se  = ws + 8396800;        // 4096

    // h1/h2 live inside the dist output region (dead before dist is written)
    float* h1 = dist;                 // 8388608  [32][256][1024]
    float* h2 = dist + 8388608;       // 8388608  [32][512][512]

    // weight transforms
    wprep_kernel<<<768,  256, 0, stream>>>(w1, wT1, 256, 256);
    wprep_kernel<<<1536, 256, 0, stream>>>(w2, wT2, 256, 512);
    wprep_kernel<<<3072, 256, 0, stream>>>(w3, wT3, 512, 512);
    wprep_kernel<<<768,  256, 0, stream>>>(w4, wT4, 512, 128);

    // conv stack
    conv_bn_lrelu<256, 256, 2048, 2, false>
        <<<dim3(16, 4, 32), 256, 0, stream>>>(x,  wT1, b1, g1, be1, m1, v1, h1);
    conv_bn_lrelu<256, 512, 1024, 2, false>
        <<<dim3(8, 8, 32), 256, 0, stream>>>(h1, wT2, b2, g2, be2, m2, v2, h2);
    conv_bn_lrelu<512, 512, 512, 2, false>
        <<<dim3(4, 8, 32), 256, 0, stream>>>(h2, wT3, b3, g3, be3, m3, v3, h3);
    conv_bn_lrelu<512, 128, 256, 1, true>
        <<<dim3(4, 2, 32), 256, 0, stream>>>(h3, wT4, b4, g4, be4, m4, v4, f);

    // transposes + norms
    transpose_kernel<<<dim3(4, 256), 256, 0, stream>>>(f,   fT, 8192, 128);
    transpose_kernel<<<dim3(4, 128), 256, 0, stream>>>(emb, eT, 4096, 128);
    sumsq_kernel<<<32, 256, 0, stream>>>(fT, sf, 8192, 128);
    sumsq_kernel<<<16, 256, 0, stream>>>(eT, se, 4096, 128);

    // distance matrix + argmin
    dist_kernel<<<dim3(64, 128), 256, 0, stream>>>(fT, eT, sf, se, dist);
    argmin_kernel<<<8192, 256, 0, stream>>>(dist, codes);
}

// Round 3
// 569.752 us; speedup vs baseline: 2.0930x; 2.0930x over previous
//
#include <hip/hip_runtime.h>
#include <cstdint>
#include <math.h>

#define EPS_BN 1e-5f
#define SLOPE 0.01f

typedef __attribute__((ext_vector_type(8))) short short8;
typedef __attribute__((ext_vector_type(16))) float f32x16;
typedef __attribute__((ext_vector_type(4))) float f32x4;

__device__ __forceinline__ unsigned short f2bf(float x) {
    unsigned u = __float_as_uint(x);
    u += 0x7fffu + ((u >> 16) & 1u);
    return (unsigned short)(u >> 16);
}
__device__ __forceinline__ float bf2f(unsigned short s) {
    return __uint_as_float(((unsigned)s) << 16);
}

typedef const __attribute__((address_space(1))) unsigned int* gas_ptr;
typedef __attribute__((address_space(3))) unsigned int* las_ptr;
__device__ __forceinline__ void glds16(const void* g, void* l) {
    __builtin_amdgcn_global_load_lds((gas_ptr)g, (las_ptr)l, 16, 0, 0);
}

// ---------- weight prep: w[O][I][3] fp32 -> fragment-ordered bf16 split slots ----
// sid = (ks*OB + ob)*2304 + slot; slot = (((t*3+s)*4+mf)*2+hi)*32+m
// value[j] = split_s( w[ob*128+mf*32+m][ks*16+hi*8+j][t] )
__global__ __launch_bounds__(256)
void wprep_mfma(const float* __restrict__ w, short* __restrict__ wbuf,
                int CIN, int COUT)
{
    int KST = CIN / 16, OB = COUT / 128;
    int total = KST * OB * 2304;
    for (int sid = blockIdx.x * 256 + threadIdx.x; sid < total;
         sid += gridDim.x * 256) {
        int slot = sid % 2304;
        int kb = sid / 2304;
        int ob = kb % OB, ks = kb / OB;
        int m = slot & 31, hi = (slot >> 5) & 1, mf = (slot >> 6) & 3;
        int ts = slot >> 8;
        int t = ts / 3, s = ts - 3 * t;
        int oc = ob * 128 + mf * 32 + m;
        int ib = ks * 16 + hi * 8;
        short8 r;
        #pragma unroll
        for (int j = 0; j < 8; ++j) {
            float v = w[((size_t)oc * CIN + ib + j) * 3 + t];
            unsigned short uh = f2bf(v);
            unsigned short out = uh;
            if (s >= 1) {
                float r1 = v - bf2f(uh);
                unsigned short um = f2bf(r1);
                out = um;
                if (s == 2) out = f2bf(r1 - bf2f(um));
            }
            r[j] = (short)out;
        }
        *(short8*)(wbuf + (size_t)sid * 8) = r;
    }
}

// ---------- BN affine prep: sc = g*inv, off = (bias - m)*sc + be ----------
__global__ void bnprep(const float* __restrict__ g, const float* __restrict__ be,
                       const float* __restrict__ m, const float* __restrict__ v,
                       const float* __restrict__ bias,
                       float* __restrict__ sc, float* __restrict__ off, int C)
{
    int i = blockIdx.x * 64 + threadIdx.x;
    if (i < C) {
        float s = g[i] / sqrtf(v[i] + EPS_BN);
        sc[i] = s;
        off[i] = (bias[i] - m[i]) * s + be[i];
    }
}

// ---------- x split: fp32 x[32][256][2048] -> 3 bf16 planes, parity slots ------
// plane sigma: [b][g(32)][arr E/O][1025 slots][8 ch]; E[1+q]=x[2q], O[q']=x[2q'-1]
__global__ __launch_bounds__(256)
void xsplit(const float* __restrict__ x, short* __restrict__ xpl)
{
    const size_t PL = (size_t)32 * 32 * 2 * 1025 * 8;
    int l = blockIdx.x * 256 + threadIdx.x;
    int g = blockIdx.y, b = blockIdx.z;
    float v[8];
    #pragma unroll
    for (int j = 0; j < 8; ++j)
        v[j] = x[((size_t)b * 256 + g * 8 + j) * 2048 + l];
    int arr = l & 1;
    int slot = arr ? (l + 1) / 2 : l / 2 + 1;
    size_t base = ((((size_t)b * 32 + g) * 2 + arr) * 1025 + slot) * 8;
    short8 rh, rm, rl;
    #pragma unroll
    for (int j = 0; j < 8; ++j) {
        unsigned short uh = f2bf(v[j]);
        float r1 = v[j] - bf2f(uh);
        unsigned short um = f2bf(r1);
        unsigned short ul = f2bf(r1 - bf2f(um));
        rh[j] = (short)uh; rm[j] = (short)um; rl[j] = (short)ul;
    }
    *(short8*)(xpl + base) = rh;
    *(short8*)(xpl + PL + base) = rm;
    *(short8*)(xpl + 2 * PL + base) = rl;
    if (l == 0) {
        short8 z;
        #pragma unroll
        for (int j = 0; j < 8; ++j) z[j] = 0;
        for (int sg = 0; sg < 3; ++sg)
            for (int a2 = 0; a2 < 2; ++a2)
                *(short8*)(xpl + sg * PL +
                           ((((size_t)b * 32 + g) * 2 + a2) * 1025) * 8) = z;
    }
}

// ---------- fused conv1d(k=3,pad=1) + BN + LReLU via 3-split bf16 MFMA ----------
// block: 128 oc x 128 pos, 4 waves (2x2), wave 64x64 as 2x2 frags of 32x32x16.
// EPI: 0 = write E/O planes (consumer stride 2), 1 = A planes (consumer stride 1),
//      2 = write fp32 f[N][128]
template<int CIN, int COUT, int LIN, int STRIDE, int EPI>
__global__ __launch_bounds__(256, 2)
void conv_mfma(const short* __restrict__ wbuf, const short* __restrict__ xpl,
               const float* __restrict__ scv, const float* __restrict__ offv,
               short* __restrict__ opl, float* __restrict__ fout)
{
    constexpr int LOUT = LIN / STRIDE;
    constexpr int KST = CIN / 16;
    constexpr int OB = COUT / 128;
    constexpr int NG = CIN / 8;
    constexpr int NARR = (STRIDE == 2) ? 2 : 1;
    constexpr int SLOTS = (STRIDE == 2) ? (LIN / 2 + 1) : (LIN + 2);
    constexpr size_t PLIN = (size_t)32 * NG * NARR * SLOTS * 8;
    constexpr int NGo = COUT / 8;
    constexpr int OSLOTS = (EPI == 0) ? (LOUT / 2 + 1) : (LOUT + 2);
    constexpr size_t PLOUT = (size_t)32 * NGo * ((EPI == 0) ? 2 : 1) * OSLOTS * 8;

    __shared__ __align__(16) char lds[63232];
    constexpr int XOFF = 36864;          // W: [0,36864)
    constexpr int SCOFF = 62208;         // X: [36864,62208); sc/off: [62208,63232)

    const int tid = threadIdx.x;
    const int lane = tid & 63;
    const int wv = tid >> 6;
    const int wm = wv >> 1, wn = wv & 1;
    const int hi = lane >> 5, n32 = lane & 31;
    const int n0 = blockIdx.x * 128;
    const int ob = blockIdx.y;
    const int o0 = ob * 128;
    const int b = blockIdx.z;

    if (tid < 128) {
        ((float*)(lds + SCOFF))[tid] = scv[o0 + tid];
        ((float*)(lds + SCOFF + 512))[tid] = offv[o0 + tid];
    }

    f32x16 acc[2][2];
    #pragma unroll
    for (int i = 0; i < 2; ++i)
        #pragma unroll
        for (int j = 0; j < 2; ++j)
            #pragma unroll
            for (int e = 0; e < 16; ++e) acc[i][j][e] = 0.0f;

    const short* wg = wbuf + (size_t)ob * 2304 * 8;
    const int lanexoff = hi * 4224 + n32 * 16;

    #pragma unroll 1
    for (int ks = 0; ks < KST; ++ks) {
        __syncthreads();
        // stage W (2304 slots of 16B)
        {
            const short* wsrc = wg + (size_t)ks * OB * 2304 * 8;
            #pragma unroll
            for (int it = 0; it < 9; ++it) {
                int slot0 = it * 256 + wv * 64;
                glds16(wsrc + (size_t)(slot0 + lane) * 8, lds + slot0 * 16);
            }
        }
        // stage X runs
        {
            int g0 = ks * 2;
            constexpr int NRUNS = (STRIDE == 2) ? 12 : 6;
            for (int r = wv; r < NRUNS; r += 4) {
                int sg, rhi, arr, start, cnt;
                if (STRIDE == 2) {
                    sg = r >> 2; rhi = (r >> 1) & 1; arr = r & 1;
                    start = arr ? n0 : (n0 + 1);
                    cnt = arr ? 129 : 128;
                } else {
                    sg = r >> 1; rhi = r & 1; arr = 0;
                    start = n0; cnt = 130;
                }
                const short* src = xpl + (size_t)sg * PLIN
                    + ((((size_t)b * NG + (g0 + rhi)) * NARR + arr) * SLOTS + start) * 8;
                char* dst = lds + XOFF + ((sg * 2 + rhi) * 2 + arr) * 2112;
                for (int c0 = 0; c0 < cnt; c0 += 64) {
                    if (lane < cnt - c0)
                        glds16(src + (size_t)(c0 + lane) * 8, dst + c0 * 16);
                }
            }
        }
        __syncthreads();
        // compute: 3 taps x 6 split-pairs x 2x2 frags
        #pragma unroll
        for (int t = 0; t < 3; ++t) {
            short8 af[3][2], bx[3][2];
            #pragma unroll
            for (int s = 0; s < 3; ++s) {
                #pragma unroll
                for (int mf = 0; mf < 2; ++mf)
                    af[s][mf] = *(const short8*)(lds +
                        (((t * 3 + s) * 4 + (wm * 2 + mf)) * 64 + lane) * 16);
                #pragma unroll
                for (int nf = 0; nf < 2; ++nf) {
                    int arr, qb;
                    if (STRIDE == 2) {
                        arr = (t == 1) ? 0 : 1;
                        qb = wn * 64 + nf * 32 + ((t == 2) ? 1 : 0);
                    } else {
                        arr = 0;
                        qb = wn * 64 + nf * 32 + t;
                    }
                    bx[s][nf] = *(const short8*)(lds + XOFF + s * 8448
                                                 + arr * 2112 + qb * 16 + lanexoff);
                }
            }
            constexpr int PA[6] = {0, 0, 1, 1, 0, 2};
            constexpr int PB[6] = {0, 1, 0, 1, 2, 0};
            #pragma unroll
            for (int p = 0; p < 6; ++p)
                #pragma unroll
                for (int mf = 0; mf < 2; ++mf)
                    #pragma unroll
                    for (int nf = 0; nf < 2; ++nf)
                        acc[mf][nf] = __builtin_amdgcn_mfma_f32_32x32x16_bf16(
                            af[PA[p]][mf], bx[PB[p]][nf], acc[mf][nf], 0, 0, 0);
        }
    }

    // ---- epilogue: affine + lrelu + (split to planes | fp32 f) via LDS transform
    #pragma unroll
    for (int half = 0; half < 2; ++half) {
        __syncthreads();
        #pragma unroll
        for (int mf = 0; mf < 2; ++mf)
            #pragma unroll
            for (int r = 0; r < 16; ++r) {
                int ocl = mf * 32 + (r & 3) + 8 * (r >> 2) + 4 * hi;
                *(float*)(lds + wv * 8704 + n32 * 272 + ocl * 4) = acc[mf][half][r];
            }
        __syncthreads();
        #pragma unroll
        for (int it = 0; it < 4; ++it) {
            int sl = tid + it * 256;
            int w = sl >> 8, rem = sl & 255, p = rem >> 3, grp = rem & 7;
            int wm_ = w >> 1, wn_ = w & 1;
            f32x4 v0 = *(f32x4*)(lds + w * 8704 + p * 272 + grp * 32);
            f32x4 v1 = *(f32x4*)(lds + w * 8704 + p * 272 + grp * 32 + 16);
            int oclb = wm_ * 64 + grp * 8;
            f32x4 s0 = *(f32x4*)(lds + SCOFF + oclb * 4);
            f32x4 s1 = *(f32x4*)(lds + SCOFF + oclb * 4 + 16);
            f32x4 q0 = *(f32x4*)(lds + SCOFF + 512 + oclb * 4);
            f32x4 q1 = *(f32x4*)(lds + SCOFF + 512 + oclb * 4 + 16);
            float y[8];
            #pragma unroll
            for (int j = 0; j < 4; ++j) {
                float a = v0[j] * s0[j] + q0[j];
                y[j] = a >= 0.0f ? a : SLOPE * a;
                float c = v1[j] * s1[j] + q1[j];
                y[4 + j] = c >= 0.0f ? c : SLOPE * c;
            }
            int pos_abs = n0 + wn_ * 64 + half * 32 + p;
            int oc_abs = o0 + oclb;
            if (EPI == 2) {
                f32x4 w0, w1;
                #pragma unroll
                for (int j = 0; j < 4; ++j) { w0[j] = y[j]; w1[j] = y[4 + j]; }
                float* fp = fout + ((size_t)(b * 256 + pos_abs)) * 128 + oc_abs;
                *(f32x4*)fp = w0;
                *(f32x4*)(fp + 4) = w1;
            } else {
                short8 rh, rm2, rl2;
                #pragma unroll
                for (int j = 0; j < 8; ++j) {
                    unsigned short uh = f2bf(y[j]);
                    float r1 = y[j] - bf2f(uh);
                    unsigned short um = f2bf(r1);
                    unsigned short ul = f2bf(r1 - bf2f(um));
                    rh[j] = (short)uh; rm2[j] = (short)um; rl2[j] = (short)ul;
                }
                int gq = oc_abs >> 3;
                size_t base;
                if (EPI == 0) {
                    int arr = pos_abs & 1;
                    int slot = arr ? (pos_abs + 1) / 2 : pos_abs / 2 + 1;
                    base = ((((size_t)b * NGo + gq) * 2 + arr) * OSLOTS + slot) * 8;
                } else {
                    base = (((size_t)b * NGo + gq) * OSLOTS + (pos_abs + 1)) * 8;
                }
                *(short8*)(opl + base) = rh;
                *(short8*)(opl + PLOUT + base) = rm2;
                *(short8*)(opl + 2 * PLOUT + base) = rl2;
            }
        }
    }

    // ---- guard slots for the consumer layer
    if (EPI == 0) {
        if (blockIdx.x == 0 && tid < 96) {
            int sg = tid / 32, r2 = tid % 32, g16 = r2 >> 1, a2 = r2 & 1;
            int gq = ob * 16 + g16;
            short8 z;
            #pragma unroll
            for (int j = 0; j < 8; ++j) z[j] = 0;
            *(short8*)(opl + (size_t)sg * PLOUT +
                       ((((size_t)b * NGo + gq) * 2 + a2) * OSLOTS) * 8) = z;
        }
    } else if (EPI == 1) {
        if (tid < 48 && (blockIdx.x == 0 || blockIdx.x == gridDim.x - 1)) {
            int sg = tid / 16, g16 = tid % 16;
            int gq = ob * 16 + g16;
            int slot = (blockIdx.x == 0) ? 0 : (OSLOTS - 1);
            short8 z;
            #pragma unroll
            for (int j = 0; j < 8; ++j) z[j] = 0;
            *(short8*)(opl + (size_t)sg * PLOUT +
                       (((size_t)b * NGo + gq) * OSLOTS + slot) * 8) = z;
        }
    }
}

// ---------- 32x32 LDS tile transpose: in[R][C] -> out[C][R] ----------
__global__ __launch_bounds__(256)
void transpose_kernel(const float* __restrict__ in, float* __restrict__ out,
                      int R, int C)
{
    __shared__ float t[32][33];
    int c0 = blockIdx.x * 32, r0 = blockIdx.y * 32;
    int x = threadIdx.x & 31, y = threadIdx.x >> 5;
    #pragma unroll
    for (int k = 0; k < 4; ++k)
        t[y + k * 8][x] = in[(size_t)(r0 + y + k * 8) * C + c0 + x];
    __syncthreads();
    #pragma unroll
    for (int k = 0; k < 4; ++k)
        out[(size_t)(c0 + y + k * 8) * R + r0 + x] = t[x][y + k * 8];
}

// ---------- row sum-of-squares from transposed layout inT[D][N] ----------
__global__ __launch_bounds__(256)
void sumsq_kernel(const float* __restrict__ inT, float* __restrict__ outv,
                  int N, int D)
{
    int n = blockIdx.x * 256 + threadIdx.x;
    if (n >= N) return;
    float s = 0.0f;
    for (int d = 0; d < D; ++d) {
        float x = inT[(size_t)d * N + n];
        s = fmaf(x, x, s);
    }
    outv[n] = s;
}

// ---------- dist[n][k] = sf[n] + se[k] - 2 * <f_n, e_k> ----------
__global__ __launch_bounds__(256)
void dist_kernel(const float* __restrict__ fT, const float* __restrict__ eT,
                 const float* __restrict__ sf, const float* __restrict__ se,
                 float* __restrict__ dist)
{
    constexpr int N = 8192, K = 4096, D = 128;
    __shared__ __align__(16) float fs[D][64];
    __shared__ __align__(16) float es[D][64];
    const int tid = threadIdx.x;
    const int k0 = blockIdx.x * 64, n0 = blockIdx.y * 64;
    const int r = tid & 63, c0 = tid >> 6;

    for (int cc = 0; cc < 32; ++cc) {
        int d = c0 * 32 + cc;
        fs[d][r] = fT[(size_t)d * N + n0 + r];
        es[d][r] = eT[(size_t)d * K + k0 + r];
    }
    __syncthreads();

    const int nt = tid & 15, kt = tid >> 4;
    float acc[4][4] = {};
    #pragma unroll 4
    for (int d = 0; d < D; ++d) {
        float4 a  = *(const float4*)&fs[d][nt * 4];
        float4 bv = *(const float4*)&es[d][kt * 4];
        float ax[4] = {a.x, a.y, a.z, a.w};
        float bx[4] = {bv.x, bv.y, bv.z, bv.w};
        #pragma unroll
        for (int i = 0; i < 4; ++i)
            #pragma unroll
            for (int j = 0; j < 4; ++j)
                acc[i][j] = fmaf(ax[i], bx[j], acc[i][j]);
    }

    #pragma unroll
    for (int i = 0; i < 4; ++i) {
        int n = n0 + nt * 4 + i;
        float sfn = sf[n];
        float o0v = (sfn + se[k0 + kt * 4 + 0]) - 2.0f * acc[i][0];
        float o1v = (sfn + se[k0 + kt * 4 + 1]) - 2.0f * acc[i][1];
        float o2v = (sfn + se[k0 + kt * 4 + 2]) - 2.0f * acc[i][2];
        float o3v = (sfn + se[k0 + kt * 4 + 3]) - 2.0f * acc[i][3];
        float4 r4 = make_float4(o0v, o1v, o2v, o3v);
        *(float4*)&dist[(size_t)n * K + k0 + kt * 4] = r4;
    }
}

// ---------- argmin over each row of dist (first-index tie-break) ----------
__global__ __launch_bounds__(256)
void argmin_kernel(const float* __restrict__ dist, float* __restrict__ codes)
{
    constexpr int K = 4096;
    __shared__ float sv[256];
    __shared__ int   si[256];
    const int n = blockIdx.x;
    const float* row = dist + (size_t)n * K;
    float bv = 3.4e38f;
    int bi = 0;
    for (int k = threadIdx.x; k < K; k += 256) {
        float v = row[k];
        if (v < bv) { bv = v; bi = k; }
    }
    sv[threadIdx.x] = bv; si[threadIdx.x] = bi;
    __syncthreads();
    for (int s = 128; s > 0; s >>= 1) {
        if (threadIdx.x < s) {
            float v2 = sv[threadIdx.x + s]; int i2 = si[threadIdx.x + s];
            if (v2 < sv[threadIdx.x] ||
                (v2 == sv[threadIdx.x] && i2 < si[threadIdx.x])) {
                sv[threadIdx.x] = v2; si[threadIdx.x] = i2;
            }
        }
        __syncthreads();
    }
    if (threadIdx.x == 0) codes[n] = (float)si[0];
}

// ---------------------------------------------------------------
extern "C" void kernel_launch(void* const* d_in, const int* in_sizes, int n_in,
                              void* d_out, int out_size, void* d_ws, size_t ws_size,
                              hipStream_t stream)
{
    const float* x   = (const float*)d_in[0];
    const float* w1  = (const float*)d_in[1];
    const float* b1  = (const float*)d_in[2];
    const float* w2  = (const float*)d_in[3];
    const float* b2  = (const float*)d_in[4];
    const float* w3  = (const float*)d_in[5];
    const float* b3  = (const float*)d_in[6];
    const float* w4  = (const float*)d_in[7];
    const float* b4  = (const float*)d_in[8];
    const float* g1  = (const float*)d_in[9];
    const float* be1 = (const float*)d_in[10];
    const float* m1  = (const float*)d_in[11];
    const float* v1  = (const float*)d_in[12];
    const float* g2  = (const float*)d_in[13];
    const float* be2 = (const float*)d_in[14];
    const float* m2  = (const float*)d_in[15];
    const float* v2  = (const float*)d_in[16];
    const float* g3  = (const float*)d_in[17];
    const float* be3 = (const float*)d_in[18];
    const float* m3  = (const float*)d_in[19];
    const float* v3  = (const float*)d_in[20];
    const float* g4  = (const float*)d_in[21];
    const float* be4 = (const float*)d_in[22];
    const float* m4  = (const float*)d_in[23];
    const float* v4  = (const float*)d_in[24];
    const float* emb = (const float*)d_in[25];

    float* outf  = (float*)d_out;
    float* codes = outf;
    float* distm = outf + 8192;

    // ---- workspace layout (bytes)
    char* wsb = (char*)d_ws;
    short* wb1 = (short*)(wsb + 0);              // 16*2*2304*16   = 1,179,648
    short* wb2 = (short*)(wsb + 1179648);        // 16*4*2304*16   = 2,359,296
    short* wb3 = (short*)(wsb + 3538944);        // 32*4*2304*16   = 4,718,592
    short* wb4 = (short*)(wsb + 8257536);        // 32*1*2304*16   = 1,179,648
    float* sc1 = (float*)(wsb + 9437184); float* off1 = sc1 + 256;
    float* sc2 = (float*)(wsb + 9439232); float* off2 = sc2 + 512;
    float* sc3 = (float*)(wsb + 9443328); float* off3 = sc3 + 512;
    float* sc4 = (float*)(wsb + 9447424); float* off4 = sc4 + 128;
    short* h1p = (short*)(wsb + 9449472);        // 3*16,809,984   = 50,429,952
    float* f   = (float*)(wsb + 59879424);       // 4,194,304
    float* fT  = (float*)(wsb + 64073728);       // 4,194,304
    float* eT  = (float*)(wsb + 68268032);       // 2,097,152
    float* sf  = (float*)(wsb + 70365184);       // 32,768
    float* se  = (float*)(wsb + 70397952);       // 16,384  -> total ~70.4 MB

    // ---- large planes live in the (dead-until-dist) dist region of d_out
    char* db = (char*)distm;
    short* xpl = (short*)db;                      // 100,761,600 B (dead after L1)
    short* h2p = (short*)db;                      // 50,528,256 B (written in L2)
    short* h3p = (short*)(db + 50528256);         // 25,362,432 B (written in L3)

    // ---- weight / bn prep
    wprep_mfma<<<288,  256, 0, stream>>>(w1, wb1, 256, 256);
    wprep_mfma<<<576,  256, 0, stream>>>(w2, wb2, 256, 512);
    wprep_mfma<<<1152, 256, 0, stream>>>(w3, wb3, 512, 512);
    wprep_mfma<<<288,  256, 0, stream>>>(w4, wb4, 512, 128);
    bnprep<<<4, 64, 0, stream>>>(g1, be1, m1, v1, b1, sc1, off1, 256);
    bnprep<<<8, 64, 0, stream>>>(g2, be2, m2, v2, b2, sc2, off2, 512);
    bnprep<<<8, 64, 0, stream>>>(g3, be3, m3, v3, b3, sc3, off3, 512);
    bnprep<<<2, 64, 0, stream>>>(g4, be4, m4, v4, b4, sc4, off4, 128);

    // ---- input split
    xsplit<<<dim3(8, 32, 32), 256, 0, stream>>>(x, xpl);

    // ---- conv stack (MFMA)
    conv_mfma<256, 256, 2048, 2, 0>
        <<<dim3(8, 2, 32), 256, 0, stream>>>(wb1, xpl, sc1, off1, h1p, nullptr);
    conv_mfma<256, 512, 1024, 2, 0>
        <<<dim3(4, 4, 32), 256, 0, stream>>>(wb2, h1p, sc2, off2, h2p, nullptr);
    conv_mfma<512, 512, 512, 2, 1>
        <<<dim3(2, 4, 32), 256, 0, stream>>>(wb3, h2p, sc3, off3, h3p, nullptr);
    conv_mfma<512, 128, 256, 1, 2>
        <<<dim3(2, 1, 32), 256, 0, stream>>>(wb4, h3p, sc4, off4, nullptr, f);

    // ---- VQ distance + argmin (unchanged fp32 path)
    transpose_kernel<<<dim3(4, 256), 256, 0, stream>>>(f,   fT, 8192, 128);
    transpose_kernel<<<dim3(4, 128), 256, 0, stream>>>(emb, eT, 4096, 128);
    sumsq_kernel<<<32, 256, 0, stream>>>(fT, sf, 8192, 128);
    sumsq_kernel<<<16, 256, 0, stream>>>(eT, se, 4096, 128);
    dist_kernel<<<dim3(64, 128), 256, 0, stream>>>(fT, eT, sf, se, distm);
    argmin_kernel<<<8192, 256, 0, stream>>>(distm, codes);
}

// Round 4
// 448.783 us; speedup vs baseline: 2.6572x; 1.2696x over previous
//
#include <hip/hip_runtime.h>
#include <cstdint>
#include <math.h>

#define EPS_BN 1e-5f
#define SLOPE 0.01f

typedef __attribute__((ext_vector_type(8))) short short8;
typedef __attribute__((ext_vector_type(16))) float f32x16;
typedef __attribute__((ext_vector_type(4))) float f32x4;

__device__ __forceinline__ unsigned short f2bf(float x) {
    unsigned u = __float_as_uint(x);
    u += 0x7fffu + ((u >> 16) & 1u);
    return (unsigned short)(u >> 16);
}
__device__ __forceinline__ float bf2f(unsigned short s) {
    return __uint_as_float(((unsigned)s) << 16);
}

typedef const __attribute__((address_space(1))) unsigned int* gas_ptr;
typedef __attribute__((address_space(3))) unsigned int* las_ptr;
__device__ __forceinline__ void glds16(const void* g, void* l) {
    __builtin_amdgcn_global_load_lds((gas_ptr)g, (las_ptr)l, 16, 0, 0);
}

// ---------- weight prep: w[O][I][3] fp32 -> fragment-ordered bf16 split slots ----
__global__ __launch_bounds__(256)
void wprep_mfma(const float* __restrict__ w, short* __restrict__ wbuf,
                int CIN, int COUT)
{
    int KST = CIN / 16, OB = COUT / 128;
    int total = KST * OB * 2304;
    for (int sid = blockIdx.x * 256 + threadIdx.x; sid < total;
         sid += gridDim.x * 256) {
        int slot = sid % 2304;
        int kb = sid / 2304;
        int ob = kb % OB, ks = kb / OB;
        int m = slot & 31, hi = (slot >> 5) & 1, mf = (slot >> 6) & 3;
        int ts = slot >> 8;
        int t = ts / 3, s = ts - 3 * t;
        int oc = ob * 128 + mf * 32 + m;
        int ib = ks * 16 + hi * 8;
        short8 r;
        #pragma unroll
        for (int j = 0; j < 8; ++j) {
            float v = w[((size_t)oc * CIN + ib + j) * 3 + t];
            unsigned short uh = f2bf(v);
            unsigned short out = uh;
            if (s >= 1) {
                float r1 = v - bf2f(uh);
                unsigned short um = f2bf(r1);
                out = um;
                if (s == 2) out = f2bf(r1 - bf2f(um));
            }
            r[j] = (short)out;
        }
        *(short8*)(wbuf + (size_t)sid * 8) = r;
    }
}

// ---------- BN affine prep ----------
__global__ void bnprep(const float* __restrict__ g, const float* __restrict__ be,
                       const float* __restrict__ m, const float* __restrict__ v,
                       const float* __restrict__ bias,
                       float* __restrict__ sc, float* __restrict__ off, int C)
{
    int i = blockIdx.x * 64 + threadIdx.x;
    if (i < C) {
        float s = g[i] / sqrtf(v[i] + EPS_BN);
        sc[i] = s;
        off[i] = (bias[i] - m[i]) * s + be[i];
    }
}

// ---------- x split: fp32 x[32][256][2048] -> 3 bf16 planes, parity slots ------
__global__ __launch_bounds__(256)
void xsplit(const float* __restrict__ x, short* __restrict__ xpl)
{
    const size_t PL = (size_t)32 * 32 * 2 * 1025 * 8;
    int l = blockIdx.x * 256 + threadIdx.x;
    int g = blockIdx.y, b = blockIdx.z;
    float v[8];
    #pragma unroll
    for (int j = 0; j < 8; ++j)
        v[j] = x[((size_t)b * 256 + g * 8 + j) * 2048 + l];
    int arr = l & 1;
    int slot = arr ? (l + 1) / 2 : l / 2 + 1;
    size_t base = ((((size_t)b * 32 + g) * 2 + arr) * 1025 + slot) * 8;
    short8 rh, rm, rl;
    #pragma unroll
    for (int j = 0; j < 8; ++j) {
        unsigned short uh = f2bf(v[j]);
        float r1 = v[j] - bf2f(uh);
        unsigned short um = f2bf(r1);
        unsigned short ul = f2bf(r1 - bf2f(um));
        rh[j] = (short)uh; rm[j] = (short)um; rl[j] = (short)ul;
    }
    *(short8*)(xpl + base) = rh;
    *(short8*)(xpl + PL + base) = rm;
    *(short8*)(xpl + 2 * PL + base) = rl;
    if (l == 0) {
        short8 z;
        #pragma unroll
        for (int j = 0; j < 8; ++j) z[j] = 0;
        for (int sg = 0; sg < 3; ++sg)
            for (int a2 = 0; a2 < 2; ++a2)
                *(short8*)(xpl + sg * PL +
                           ((((size_t)b * 32 + g) * 2 + a2) * 1025) * 8) = z;
    }
}

// ---------- fused conv1d(k=3,pad=1) + BN + LReLU via 3-split bf16 MFMA ----------
template<int CIN, int COUT, int LIN, int STRIDE, int EPI>
__global__ __launch_bounds__(256, 2)
void conv_mfma(const short* __restrict__ wbuf, const short* __restrict__ xpl,
               const float* __restrict__ scv, const float* __restrict__ offv,
               short* __restrict__ opl, float* __restrict__ fout)
{
    constexpr int LOUT = LIN / STRIDE;
    constexpr int KST = CIN / 16;
    constexpr int OB = COUT / 128;
    constexpr int NG = CIN / 8;
    constexpr int NARR = (STRIDE == 2) ? 2 : 1;
    constexpr int SLOTS = (STRIDE == 2) ? (LIN / 2 + 1) : (LIN + 2);
    constexpr size_t PLIN = (size_t)32 * NG * NARR * SLOTS * 8;
    constexpr int NGo = COUT / 8;
    constexpr int OSLOTS = (EPI == 0) ? (LOUT / 2 + 1) : (LOUT + 2);
    constexpr size_t PLOUT = (size_t)32 * NGo * ((EPI == 0) ? 2 : 1) * OSLOTS * 8;

    __shared__ __align__(16) char lds[63232];
    constexpr int XOFF = 36864;
    constexpr int SCOFF = 62208;

    const int tid = threadIdx.x;
    const int lane = tid & 63;
    const int wv = tid >> 6;
    const int wm = wv >> 1, wn = wv & 1;
    const int hi = lane >> 5, n32 = lane & 31;
    const int n0 = blockIdx.x * 128;
    const int ob = blockIdx.y;
    const int o0 = ob * 128;
    const int b = blockIdx.z;

    if (tid < 128) {
        ((float*)(lds + SCOFF))[tid] = scv[o0 + tid];
        ((float*)(lds + SCOFF + 512))[tid] = offv[o0 + tid];
    }

    f32x16 acc[2][2];
    #pragma unroll
    for (int i = 0; i < 2; ++i)
        #pragma unroll
        for (int j = 0; j < 2; ++j)
            #pragma unroll
            for (int e = 0; e < 16; ++e) acc[i][j][e] = 0.0f;

    const short* wg = wbuf + (size_t)ob * 2304 * 8;
    const int lanexoff = hi * 4224 + n32 * 16;

    #pragma unroll 1
    for (int ks = 0; ks < KST; ++ks) {
        __syncthreads();
        {
            const short* wsrc = wg + (size_t)ks * OB * 2304 * 8;
            #pragma unroll
            for (int it = 0; it < 9; ++it) {
                int slot0 = it * 256 + wv * 64;
                glds16(wsrc + (size_t)(slot0 + lane) * 8, lds + slot0 * 16);
            }
        }
        {
            int g0 = ks * 2;
            constexpr int NRUNS = (STRIDE == 2) ? 12 : 6;
            for (int r = wv; r < NRUNS; r += 4) {
                int sg, rhi, arr, start, cnt;
                if (STRIDE == 2) {
                    sg = r >> 2; rhi = (r >> 1) & 1; arr = r & 1;
                    start = arr ? n0 : (n0 + 1);
                    cnt = arr ? 129 : 128;
                } else {
                    sg = r >> 1; rhi = r & 1; arr = 0;
                    start = n0; cnt = 130;
                }
                const short* src = xpl + (size_t)sg * PLIN
                    + ((((size_t)b * NG + (g0 + rhi)) * NARR + arr) * SLOTS + start) * 8;
                char* dst = lds + XOFF + ((sg * 2 + rhi) * 2 + arr) * 2112;
                for (int c0 = 0; c0 < cnt; c0 += 64) {
                    if (lane < cnt - c0)
                        glds16(src + (size_t)(c0 + lane) * 8, dst + c0 * 16);
                }
            }
        }
        __syncthreads();
        #pragma unroll
        for (int t = 0; t < 3; ++t) {
            short8 af[3][2], bx[3][2];
            #pragma unroll
            for (int s = 0; s < 3; ++s) {
                #pragma unroll
                for (int mf = 0; mf < 2; ++mf)
                    af[s][mf] = *(const short8*)(lds +
                        (((t * 3 + s) * 4 + (wm * 2 + mf)) * 64 + lane) * 16);
                #pragma unroll
                for (int nf = 0; nf < 2; ++nf) {
                    int arr, qb;
                    if (STRIDE == 2) {
                        arr = (t == 1) ? 0 : 1;
                        qb = wn * 64 + nf * 32 + ((t == 2) ? 1 : 0);
                    } else {
                        arr = 0;
                        qb = wn * 64 + nf * 32 + t;
                    }
                    bx[s][nf] = *(const short8*)(lds + XOFF + s * 8448
                                                 + arr * 2112 + qb * 16 + lanexoff);
                }
            }
            constexpr int PA[6] = {0, 0, 1, 1, 0, 2};
            constexpr int PB[6] = {0, 1, 0, 1, 2, 0};
            #pragma unroll
            for (int p = 0; p < 6; ++p)
                #pragma unroll
                for (int mf = 0; mf < 2; ++mf)
                    #pragma unroll
                    for (int nf = 0; nf < 2; ++nf)
                        acc[mf][nf] = __builtin_amdgcn_mfma_f32_32x32x16_bf16(
                            af[PA[p]][mf], bx[PB[p]][nf], acc[mf][nf], 0, 0, 0);
        }
    }

    #pragma unroll
    for (int half = 0; half < 2; ++half) {
        __syncthreads();
        #pragma unroll
        for (int mf = 0; mf < 2; ++mf)
            #pragma unroll
            for (int r = 0; r < 16; ++r) {
                int ocl = mf * 32 + (r & 3) + 8 * (r >> 2) + 4 * hi;
                *(float*)(lds + wv * 8704 + n32 * 272 + ocl * 4) = acc[mf][half][r];
            }
        __syncthreads();
        #pragma unroll
        for (int it = 0; it < 4; ++it) {
            int sl = tid + it * 256;
            int w = sl >> 8, rem = sl & 255, p = rem >> 3, grp = rem & 7;
            int wm_ = w >> 1, wn_ = w & 1;
            f32x4 v0 = *(f32x4*)(lds + w * 8704 + p * 272 + grp * 32);
            f32x4 v1 = *(f32x4*)(lds + w * 8704 + p * 272 + grp * 32 + 16);
            int oclb = wm_ * 64 + grp * 8;
            f32x4 s0 = *(f32x4*)(lds + SCOFF + oclb * 4);
            f32x4 s1 = *(f32x4*)(lds + SCOFF + oclb * 4 + 16);
            f32x4 q0 = *(f32x4*)(lds + SCOFF + 512 + oclb * 4);
            f32x4 q1 = *(f32x4*)(lds + SCOFF + 512 + oclb * 4 + 16);
            float y[8];
            #pragma unroll
            for (int j = 0; j < 4; ++j) {
                float a = v0[j] * s0[j] + q0[j];
                y[j] = a >= 0.0f ? a : SLOPE * a;
                float c = v1[j] * s1[j] + q1[j];
                y[4 + j] = c >= 0.0f ? c : SLOPE * c;
            }
            int pos_abs = n0 + wn_ * 64 + half * 32 + p;
            int oc_abs = o0 + oclb;
            if (EPI == 2) {
                f32x4 w0, w1;
                #pragma unroll
                for (int j = 0; j < 4; ++j) { w0[j] = y[j]; w1[j] = y[4 + j]; }
                float* fp = fout + ((size_t)(b * 256 + pos_abs)) * 128 + oc_abs;
                *(f32x4*)fp = w0;
                *(f32x4*)(fp + 4) = w1;
            } else {
                short8 rh, rm2, rl2;
                #pragma unroll
                for (int j = 0; j < 8; ++j) {
                    unsigned short uh = f2bf(y[j]);
                    float r1 = y[j] - bf2f(uh);
                    unsigned short um = f2bf(r1);
                    unsigned short ul = f2bf(r1 - bf2f(um));
                    rh[j] = (short)uh; rm2[j] = (short)um; rl2[j] = (short)ul;
                }
                int gq = oc_abs >> 3;
                size_t base;
                if (EPI == 0) {
                    int arr = pos_abs & 1;
                    int slot = arr ? (pos_abs + 1) / 2 : pos_abs / 2 + 1;
                    base = ((((size_t)b * NGo + gq) * 2 + arr) * OSLOTS + slot) * 8;
                } else {
                    base = (((size_t)b * NGo + gq) * OSLOTS + (pos_abs + 1)) * 8;
                }
                *(short8*)(opl + base) = rh;
                *(short8*)(opl + PLOUT + base) = rm2;
                *(short8*)(opl + 2 * PLOUT + base) = rl2;
            }
        }
    }

    if (EPI == 0) {
        if (blockIdx.x == 0 && tid < 96) {
            int sg = tid / 32, r2 = tid % 32, g16 = r2 >> 1, a2 = r2 & 1;
            int gq = ob * 16 + g16;
            short8 z;
            #pragma unroll
            for (int j = 0; j < 8; ++j) z[j] = 0;
            *(short8*)(opl + (size_t)sg * PLOUT +
                       ((((size_t)b * NGo + gq) * 2 + a2) * OSLOTS) * 8) = z;
        }
    } else if (EPI == 1) {
        if (tid < 48 && (blockIdx.x == 0 || blockIdx.x == gridDim.x - 1)) {
            int sg = tid / 16, g16 = tid % 16;
            int gq = ob * 16 + g16;
            int slot = (blockIdx.x == 0) ? 0 : (OSLOTS - 1);
            short8 z;
            #pragma unroll
            for (int j = 0; j < 8; ++j) z[j] = 0;
            *(short8*)(opl + (size_t)sg * PLOUT +
                       (((size_t)b * NGo + gq) * OSLOTS + slot) * 8) = z;
        }
    }
}

// ---------- row split: src[N][128] fp32 -> 3 bf16 planes (fragment order) + sumsq
// slot(nb,ks,hi,m) = ((nb*8+ks)*2+hi)*32+m ; elem j: d = ks*16+hi*8+j ; m=n&31
__global__ __launch_bounds__(256)
void split_kernel(const float* __restrict__ src, int nrows,
                  short* __restrict__ ph, short* __restrict__ pm,
                  short* __restrict__ pl, float* __restrict__ sumv)
{
    int t = blockIdx.x * 256 + threadIdx.x;
    int n = t >> 4, g = t & 15;
    if (n >= nrows) return;
    const float* rowp = src + (size_t)n * 128 + g * 8;
    float4 v0 = *(const float4*)rowp;
    float4 v1 = *(const float4*)(rowp + 4);
    float vv[8] = {v0.x, v0.y, v0.z, v0.w, v1.x, v1.y, v1.z, v1.w};
    short8 rh, rm, rl;
    float ss = 0.0f;
    #pragma unroll
    for (int j = 0; j < 8; ++j) {
        float v = vv[j];
        ss = fmaf(v, v, ss);
        unsigned short uh = f2bf(v);
        float r1 = v - bf2f(uh);
        unsigned short um = f2bf(r1);
        unsigned short ul = f2bf(r1 - bf2f(um));
        rh[j] = (short)uh; rm[j] = (short)um; rl[j] = (short)ul;
    }
    int nb = n >> 5, m = n & 31, ks = g >> 1, hi = g & 1;
    size_t slot = ((((size_t)nb * 8 + ks) * 2 + hi) * 32 + m) * 8;
    *(short8*)(ph + slot) = rh;
    *(short8*)(pm + slot) = rm;
    *(short8*)(pl + slot) = rl;
    #pragma unroll
    for (int mk = 8; mk; mk >>= 1) ss += __shfl_xor(ss, mk);
    if (g == 0) sumv[n] = ss;
}

// ---------- dist tile (128n x 64k) via 6-term bf16-split MFMA + fused argmin ----
__global__ __launch_bounds__(256, 1)
void distmin_kernel(const short* __restrict__ fh, const short* __restrict__ fm,
                    const short* __restrict__ fl, const short* __restrict__ eh,
                    const short* __restrict__ em, const short* __restrict__ el,
                    const float* __restrict__ sf, const float* __restrict__ se,
                    float* __restrict__ dist, unsigned long long* __restrict__ mp)
{
    __shared__ __align__(16) char lds[147456];
    const int tid = threadIdx.x;
    const int lane = tid & 63;
    const int wv = tid >> 6;
    const int wm = wv >> 1, wn = wv & 1;
    const int hi = lane >> 5, n32 = lane & 31;
    const int kb = blockIdx.x;   // 0..63  (k-tile of 64)
    const int nb = blockIdx.y;   // 0..63  (n-tile of 128)

    // stage: f planes 32KB each (2048 slots), e planes 16KB each (1024 slots)
    {
        const short* s0 = fh + (size_t)nb * 16384;
        const short* s1 = fm + (size_t)nb * 16384;
        const short* s2 = fl + (size_t)nb * 16384;
        #pragma unroll
        for (int it = 0; it < 8; ++it) {
            int slot0 = it * 256 + wv * 64;
            glds16(s0 + (size_t)(slot0 + lane) * 8, lds + slot0 * 16);
            glds16(s1 + (size_t)(slot0 + lane) * 8, lds + 32768 + slot0 * 16);
            glds16(s2 + (size_t)(slot0 + lane) * 8, lds + 65536 + slot0 * 16);
        }
        const short* s3 = eh + (size_t)kb * 8192;
        const short* s4 = em + (size_t)kb * 8192;
        const short* s5 = el + (size_t)kb * 8192;
        #pragma unroll
        for (int it = 0; it < 4; ++it) {
            int slot0 = it * 256 + wv * 64;
            glds16(s3 + (size_t)(slot0 + lane) * 8, lds + 98304 + slot0 * 16);
            glds16(s4 + (size_t)(slot0 + lane) * 8, lds + 114688 + slot0 * 16);
            glds16(s5 + (size_t)(slot0 + lane) * 8, lds + 131072 + slot0 * 16);
        }
    }
    __syncthreads();

    f32x16 acc[2];
    #pragma unroll
    for (int i = 0; i < 2; ++i)
        #pragma unroll
        for (int e = 0; e < 16; ++e) acc[i][e] = 0.0f;

    #pragma unroll
    for (int ks = 0; ks < 8; ++ks) {
        short8 af[3][2], bx[3];
        #pragma unroll
        for (int s = 0; s < 3; ++s) {
            #pragma unroll
            for (int mf = 0; mf < 2; ++mf)
                af[s][mf] = *(const short8*)(lds + s * 32768 +
                    (((wm * 2 + mf) * 8 + ks) * 64 + lane) * 16);
            bx[s] = *(const short8*)(lds + 98304 + s * 16384 +
                    ((wn * 8 + ks) * 64 + lane) * 16);
        }
        constexpr int PA[6] = {0, 0, 1, 1, 0, 2};
        constexpr int PB[6] = {0, 1, 0, 1, 2, 0};
        #pragma unroll
        for (int p = 0; p < 6; ++p)
            #pragma unroll
            for (int mf = 0; mf < 2; ++mf)
                acc[mf] = __builtin_amdgcn_mfma_f32_32x32x16_bf16(
                    af[PA[p]][mf], bx[PB[p]], acc[mf], 0, 0, 0);
    }
    __syncthreads();

    // epilogue: dist = (sf+se) - 2*dot ; per-row block-partial argmin via LDS
    unsigned long long* cand = (unsigned long long*)lds;  // [128][64]
    const int n_blk = nb * 128;
    const int kcol = kb * 64 + wn * 32 + n32;
    const float sev = se[kcol];
    #pragma unroll
    for (int mf = 0; mf < 2; ++mf) {
        #pragma unroll
        for (int r = 0; r < 16; ++r) {
            int nloc = wm * 64 + mf * 32 + (r & 3) + 8 * (r >> 2) + 4 * hi;
            int n = n_blk + nloc;
            float v = (sf[n] + sev) - 2.0f * acc[mf][r];
            dist[(size_t)n * 4096 + kcol] = v;
            unsigned long long p =
                (((unsigned long long)__float_as_uint(v)) << 32) | (unsigned)kcol;
            cand[nloc * 64 + wn * 32 + n32] = p;
        }
    }
    __syncthreads();
    {
        int row = tid >> 1, h = tid & 1;
        unsigned long long best = ~0ULL;
        #pragma unroll
        for (int i = 0; i < 32; ++i) {
            int c = h * 32 + ((i + row) & 31);   // rotation: avoid bank degeneracy
            unsigned long long cv = cand[row * 64 + c];
            best = cv < best ? cv : best;
        }
        unsigned lo = (unsigned)best, hw = (unsigned)(best >> 32);
        unsigned lo2 = __shfl_xor(lo, 1), hw2 = __shfl_xor(hw, 1);
        unsigned long long ob = (((unsigned long long)hw2) << 32) | lo2;
        if (ob < best) best = ob;
        if (h == 0) atomicMin(mp + n_blk + row, best);
    }
}

// ---------- unpack codes ----------
__global__ __launch_bounds__(256)
void codes_kernel(const unsigned long long* __restrict__ mp,
                  float* __restrict__ codes)
{
    int n = blockIdx.x * 256 + threadIdx.x;
    if (n < 8192) codes[n] = (float)(unsigned)(mp[n] & 0xffffffffULL);
}

// ---------------------------------------------------------------
extern "C" void kernel_launch(void* const* d_in, const int* in_sizes, int n_in,
                              void* d_out, int out_size, void* d_ws, size_t ws_size,
                              hipStream_t stream)
{
    const float* x   = (const float*)d_in[0];
    const float* w1  = (const float*)d_in[1];
    const float* b1  = (const float*)d_in[2];
    const float* w2  = (const float*)d_in[3];
    const float* b2  = (const float*)d_in[4];
    const float* w3  = (const float*)d_in[5];
    const float* b3  = (const float*)d_in[6];
    const float* w4  = (const float*)d_in[7];
    const float* b4  = (const float*)d_in[8];
    const float* g1  = (const float*)d_in[9];
    const float* be1 = (const float*)d_in[10];
    const float* m1  = (const float*)d_in[11];
    const float* v1  = (const float*)d_in[12];
    const float* g2  = (const float*)d_in[13];
    const float* be2 = (const float*)d_in[14];
    const float* m2  = (const float*)d_in[15];
    const float* v2  = (const float*)d_in[16];
    const float* g3  = (const float*)d_in[17];
    const float* be3 = (const float*)d_in[18];
    const float* m3  = (const float*)d_in[19];
    const float* v3  = (const float*)d_in[20];
    const float* g4  = (const float*)d_in[21];
    const float* be4 = (const float*)d_in[22];
    const float* m4  = (const float*)d_in[23];
    const float* v4  = (const float*)d_in[24];
    const float* emb = (const float*)d_in[25];

    float* outf  = (float*)d_out;
    float* codes = outf;
    float* distm = outf + 8192;

    // ---- workspace layout (bytes)
    char* wsb = (char*)d_ws;
    short* wb1 = (short*)(wsb + 0);
    short* wb2 = (short*)(wsb + 1179648);
    short* wb3 = (short*)(wsb + 3538944);
    short* wb4 = (short*)(wsb + 8257536);
    float* sc1 = (float*)(wsb + 9437184); float* off1 = sc1 + 256;
    float* sc2 = (float*)(wsb + 9439232); float* off2 = sc2 + 512;
    float* sc3 = (float*)(wsb + 9443328); float* off3 = sc3 + 512;
    float* sc4 = (float*)(wsb + 9447424); float* off4 = sc4 + 128;
    short* h1p = (short*)(wsb + 9449472);        // 50,429,952
    short* fh  = (short*)(wsb + 59879424);       // 2,097,152 each
    short* fm  = (short*)(wsb + 61976576);
    short* fl  = (short*)(wsb + 64073728);
    short* eh  = (short*)(wsb + 66170880);       // 1,048,576 each
    short* em  = (short*)(wsb + 67219456);
    short* el  = (short*)(wsb + 68268032);
    float* sf  = (float*)(wsb + 69316608);
    float* se  = (float*)(wsb + 69349376);
    unsigned long long* mp = (unsigned long long*)(wsb + 69365760);  // 65,536

    // ---- large scratch in the (dead-until-dist) dist region of d_out
    char* db = (char*)distm;
    short* xpl = (short*)db;                      // L1 input planes
    short* h2p = (short*)db;                      // L2 output planes
    short* h3p = (short*)(db + 50528256);         // L3 output planes
    float* f   = (float*)(db + 80000000);         // fp32 features [8192][128]

    // ---- prep
    wprep_mfma<<<288,  256, 0, stream>>>(w1, wb1, 256, 256);
    wprep_mfma<<<576,  256, 0, stream>>>(w2, wb2, 256, 512);
    wprep_mfma<<<1152, 256, 0, stream>>>(w3, wb3, 512, 512);
    wprep_mfma<<<288,  256, 0, stream>>>(w4, wb4, 512, 128);
    bnprep<<<4, 64, 0, stream>>>(g1, be1, m1, v1, b1, sc1, off1, 256);
    bnprep<<<8, 64, 0, stream>>>(g2, be2, m2, v2, b2, sc2, off2, 512);
    bnprep<<<8, 64, 0, stream>>>(g3, be3, m3, v3, b3, sc3, off3, 512);
    bnprep<<<2, 64, 0, stream>>>(g4, be4, m4, v4, b4, sc4, off4, 128);
    hipMemsetAsync(mp, 0xFF, 8192 * 8, stream);
    split_kernel<<<256, 256, 0, stream>>>(emb, 4096, eh, em, el, se);

    // ---- input split + conv stack
    xsplit<<<dim3(8, 32, 32), 256, 0, stream>>>(x, xpl);
    conv_mfma<256, 256, 2048, 2, 0>
        <<<dim3(8, 2, 32), 256, 0, stream>>>(wb1, xpl, sc1, off1, h1p, nullptr);
    conv_mfma<256, 512, 1024, 2, 0>
        <<<dim3(4, 4, 32), 256, 0, stream>>>(wb2, h1p, sc2, off2, h2p, nullptr);
    conv_mfma<512, 512, 512, 2, 1>
        <<<dim3(2, 4, 32), 256, 0, stream>>>(wb3, h2p, sc3, off3, h3p, nullptr);
    conv_mfma<512, 128, 256, 1, 2>
        <<<dim3(2, 1, 32), 256, 0, stream>>>(wb4, h3p, sc4, off4, nullptr, f);

    // ---- VQ: split f, MFMA distance + fused argmin, unpack codes
    split_kernel<<<512, 256, 0, stream>>>(f, 8192, fh, fm, fl, sf);
    distmin_kernel<<<dim3(64, 64), 256, 0, stream>>>(fh, fm, fl, eh, em, el,
                                                     sf, se, distm, mp);
    codes_kernel<<<32, 256, 0, stream>>>(mp, codes);
}

// Round 5
// 416.320 us; speedup vs baseline: 2.8644x; 1.0780x over previous
//
#include <hip/hip_runtime.h>
#include <cstdint>
#include <math.h>

#define EPS_BN 1e-5f
#define SLOPE 0.01f

typedef __attribute__((ext_vector_type(8))) short short8;
typedef __attribute__((ext_vector_type(16))) float f32x16;
typedef __attribute__((ext_vector_type(4))) float f32x4;

__device__ __forceinline__ unsigned short f2bf(float x) {
    unsigned u = __float_as_uint(x);
    u += 0x7fffu + ((u >> 16) & 1u);
    return (unsigned short)(u >> 16);
}
__device__ __forceinline__ float bf2f(unsigned short s) {
    return __uint_as_float(((unsigned)s) << 16);
}

typedef const __attribute__((address_space(1))) unsigned int* gas_ptr;
typedef __attribute__((address_space(3))) unsigned int* las_ptr;
__device__ __forceinline__ void glds16(const void* g, void* l) {
    __builtin_amdgcn_global_load_lds((gas_ptr)g, (las_ptr)l, 16, 0, 0);
}

// ---------- weight prep: w[O][I][3] fp32 -> fragment-ordered bf16 split slots ----
__global__ __launch_bounds__(256)
void wprep_mfma(const float* __restrict__ w, short* __restrict__ wbuf,
                int CIN, int COUT)
{
    int KST = CIN / 16, OB = COUT / 128;
    int total = KST * OB * 2304;
    for (int sid = blockIdx.x * 256 + threadIdx.x; sid < total;
         sid += gridDim.x * 256) {
        int slot = sid % 2304;
        int kb = sid / 2304;
        int ob = kb % OB, ks = kb / OB;
        int m = slot & 31, hi = (slot >> 5) & 1, mf = (slot >> 6) & 3;
        int ts = slot >> 8;
        int t = ts / 3, s = ts - 3 * t;
        int oc = ob * 128 + mf * 32 + m;
        int ib = ks * 16 + hi * 8;
        short8 r;
        #pragma unroll
        for (int j = 0; j < 8; ++j) {
            float v = w[((size_t)oc * CIN + ib + j) * 3 + t];
            unsigned short uh = f2bf(v);
            unsigned short out = uh;
            if (s >= 1) {
                float r1 = v - bf2f(uh);
                unsigned short um = f2bf(r1);
                out = um;
                if (s == 2) out = f2bf(r1 - bf2f(um));
            }
            r[j] = (short)out;
        }
        *(short8*)(wbuf + (size_t)sid * 8) = r;
    }
}

// ---------- BN affine prep ----------
__global__ void bnprep(const float* __restrict__ g, const float* __restrict__ be,
                       const float* __restrict__ m, const float* __restrict__ v,
                       const float* __restrict__ bias,
                       float* __restrict__ sc, float* __restrict__ off, int C)
{
    int i = blockIdx.x * 64 + threadIdx.x;
    if (i < C) {
        float s = g[i] / sqrtf(v[i] + EPS_BN);
        sc[i] = s;
        off[i] = (bias[i] - m[i]) * s + be[i];
    }
}

// ---------- x split: fp32 x[32][256][2048] -> 3 bf16 planes, parity slots ------
__global__ __launch_bounds__(256)
void xsplit(const float* __restrict__ x, short* __restrict__ xpl)
{
    const size_t PL = (size_t)32 * 32 * 2 * 1025 * 8;
    int l = blockIdx.x * 256 + threadIdx.x;
    int g = blockIdx.y, b = blockIdx.z;
    float v[8];
    #pragma unroll
    for (int j = 0; j < 8; ++j)
        v[j] = x[((size_t)b * 256 + g * 8 + j) * 2048 + l];
    int arr = l & 1;
    int slot = arr ? (l + 1) / 2 : l / 2 + 1;
    size_t base = ((((size_t)b * 32 + g) * 2 + arr) * 1025 + slot) * 8;
    short8 rh, rm, rl;
    #pragma unroll
    for (int j = 0; j < 8; ++j) {
        unsigned short uh = f2bf(v[j]);
        float r1 = v[j] - bf2f(uh);
        unsigned short um = f2bf(r1);
        unsigned short ul = f2bf(r1 - bf2f(um));
        rh[j] = (short)uh; rm[j] = (short)um; rl[j] = (short)ul;
    }
    *(short8*)(xpl + base) = rh;
    *(short8*)(xpl + PL + base) = rm;
    *(short8*)(xpl + 2 * PL + base) = rl;
    if (l == 0) {
        short8 z;
        #pragma unroll
        for (int j = 0; j < 8; ++j) z[j] = 0;
        for (int sg = 0; sg < 3; ++sg)
            for (int a2 = 0; a2 < 2; ++a2)
                *(short8*)(xpl + sg * PL +
                           ((((size_t)b * 32 + g) * 2 + a2) * 1025) * 8) = z;
    }
}

// ---------- fused conv1d(k=3,pad=1) + BN + LReLU via 3-split bf16 MFMA ----------
template<int CIN, int COUT, int LIN, int STRIDE, int EPI>
__global__ __launch_bounds__(256, 2)
void conv_mfma(const short* __restrict__ wbuf, const short* __restrict__ xpl,
               const float* __restrict__ scv, const float* __restrict__ offv,
               short* __restrict__ opl, float* __restrict__ fout)
{
    constexpr int LOUT = LIN / STRIDE;
    constexpr int KST = CIN / 16;
    constexpr int OB = COUT / 128;
    constexpr int NG = CIN / 8;
    constexpr int NARR = (STRIDE == 2) ? 2 : 1;
    constexpr int SLOTS = (STRIDE == 2) ? (LIN / 2 + 1) : (LIN + 2);
    constexpr size_t PLIN = (size_t)32 * NG * NARR * SLOTS * 8;
    constexpr int NGo = COUT / 8;
    constexpr int OSLOTS = (EPI == 0) ? (LOUT / 2 + 1) : (LOUT + 2);
    constexpr size_t PLOUT = (size_t)32 * NGo * ((EPI == 0) ? 2 : 1) * OSLOTS * 8;

    __shared__ __align__(16) char lds[63232];
    constexpr int XOFF = 36864;
    constexpr int SCOFF = 62208;

    const int tid = threadIdx.x;
    const int lane = tid & 63;
    const int wv = tid >> 6;
    const int wm = wv >> 1, wn = wv & 1;
    const int hi = lane >> 5, n32 = lane & 31;
    const int n0 = blockIdx.x * 128;
    const int ob = blockIdx.y;
    const int o0 = ob * 128;
    const int b = blockIdx.z;

    if (tid < 128) {
        ((float*)(lds + SCOFF))[tid] = scv[o0 + tid];
        ((float*)(lds + SCOFF + 512))[tid] = offv[o0 + tid];
    }

    f32x16 acc[2][2];
    #pragma unroll
    for (int i = 0; i < 2; ++i)
        #pragma unroll
        for (int j = 0; j < 2; ++j)
            #pragma unroll
            for (int e = 0; e < 16; ++e) acc[i][j][e] = 0.0f;

    const short* wg = wbuf + (size_t)ob * 2304 * 8;
    const int lanexoff = hi * 4224 + n32 * 16;

    #pragma unroll 1
    for (int ks = 0; ks < KST; ++ks) {
        __syncthreads();
        {
            const short* wsrc = wg + (size_t)ks * OB * 2304 * 8;
            #pragma unroll
            for (int it = 0; it < 9; ++it) {
                int slot0 = it * 256 + wv * 64;
                glds16(wsrc + (size_t)(slot0 + lane) * 8, lds + slot0 * 16);
            }
        }
        {
            int g0 = ks * 2;
            constexpr int NRUNS = (STRIDE == 2) ? 12 : 6;
            for (int r = wv; r < NRUNS; r += 4) {
                int sg, rhi, arr, start, cnt;
                if (STRIDE == 2) {
                    sg = r >> 2; rhi = (r >> 1) & 1; arr = r & 1;
                    start = arr ? n0 : (n0 + 1);
                    cnt = arr ? 129 : 128;
                } else {
                    sg = r >> 1; rhi = r & 1; arr = 0;
                    start = n0; cnt = 130;
                }
                const short* src = xpl + (size_t)sg * PLIN
                    + ((((size_t)b * NG + (g0 + rhi)) * NARR + arr) * SLOTS + start) * 8;
                char* dst = lds + XOFF + ((sg * 2 + rhi) * 2 + arr) * 2112;
                for (int c0 = 0; c0 < cnt; c0 += 64) {
                    if (lane < cnt - c0)
                        glds16(src + (size_t)(c0 + lane) * 8, dst + c0 * 16);
                }
            }
        }
        __syncthreads();
        #pragma unroll
        for (int t = 0; t < 3; ++t) {
            short8 af[3][2], bx[3][2];
            #pragma unroll
            for (int s = 0; s < 3; ++s) {
                #pragma unroll
                for (int mf = 0; mf < 2; ++mf)
                    af[s][mf] = *(const short8*)(lds +
                        (((t * 3 + s) * 4 + (wm * 2 + mf)) * 64 + lane) * 16);
                #pragma unroll
                for (int nf = 0; nf < 2; ++nf) {
                    int arr, qb;
                    if (STRIDE == 2) {
                        arr = (t == 1) ? 0 : 1;
                        qb = wn * 64 + nf * 32 + ((t == 2) ? 1 : 0);
                    } else {
                        arr = 0;
                        qb = wn * 64 + nf * 32 + t;
                    }
                    bx[s][nf] = *(const short8*)(lds + XOFF + s * 8448
                                                 + arr * 2112 + qb * 16 + lanexoff);
                }
            }
            constexpr int PA[6] = {0, 0, 1, 1, 0, 2};
            constexpr int PB[6] = {0, 1, 0, 1, 2, 0};
            #pragma unroll
            for (int p = 0; p < 6; ++p)
                #pragma unroll
                for (int mf = 0; mf < 2; ++mf)
                    #pragma unroll
                    for (int nf = 0; nf < 2; ++nf)
                        acc[mf][nf] = __builtin_amdgcn_mfma_f32_32x32x16_bf16(
                            af[PA[p]][mf], bx[PB[p]][nf], acc[mf][nf], 0, 0, 0);
        }
    }

    #pragma unroll
    for (int half = 0; half < 2; ++half) {
        __syncthreads();
        #pragma unroll
        for (int mf = 0; mf < 2; ++mf)
            #pragma unroll
            for (int r = 0; r < 16; ++r) {
                int ocl = mf * 32 + (r & 3) + 8 * (r >> 2) + 4 * hi;
                *(float*)(lds + wv * 8704 + n32 * 272 + ocl * 4) = acc[mf][half][r];
            }
        __syncthreads();
        #pragma unroll
        for (int it = 0; it < 4; ++it) {
            int sl = tid + it * 256;
            int w = sl >> 8, rem = sl & 255, p = rem >> 3, grp = rem & 7;
            int wm_ = w >> 1, wn_ = w & 1;
            f32x4 v0 = *(f32x4*)(lds + w * 8704 + p * 272 + grp * 32);
            f32x4 v1 = *(f32x4*)(lds + w * 8704 + p * 272 + grp * 32 + 16);
            int oclb = wm_ * 64 + grp * 8;
            f32x4 s0 = *(f32x4*)(lds + SCOFF + oclb * 4);
            f32x4 s1 = *(f32x4*)(lds + SCOFF + oclb * 4 + 16);
            f32x4 q0 = *(f32x4*)(lds + SCOFF + 512 + oclb * 4);
            f32x4 q1 = *(f32x4*)(lds + SCOFF + 512 + oclb * 4 + 16);
            float y[8];
            #pragma unroll
            for (int j = 0; j < 4; ++j) {
                float a = v0[j] * s0[j] + q0[j];
                y[j] = a >= 0.0f ? a : SLOPE * a;
                float c = v1[j] * s1[j] + q1[j];
                y[4 + j] = c >= 0.0f ? c : SLOPE * c;
            }
            int pos_abs = n0 + wn_ * 64 + half * 32 + p;
            int oc_abs = o0 + oclb;
            if (EPI == 2) {
                f32x4 w0, w1;
                #pragma unroll
                for (int j = 0; j < 4; ++j) { w0[j] = y[j]; w1[j] = y[4 + j]; }
                float* fp = fout + ((size_t)(b * 256 + pos_abs)) * 128 + oc_abs;
                *(f32x4*)fp = w0;
                *(f32x4*)(fp + 4) = w1;
            } else {
                short8 rh, rm2, rl2;
                #pragma unroll
                for (int j = 0; j < 8; ++j) {
                    unsigned short uh = f2bf(y[j]);
                    float r1 = y[j] - bf2f(uh);
                    unsigned short um = f2bf(r1);
                    unsigned short ul = f2bf(r1 - bf2f(um));
                    rh[j] = (short)uh; rm2[j] = (short)um; rl2[j] = (short)ul;
                }
                int gq = oc_abs >> 3;
                size_t base;
                if (EPI == 0) {
                    int arr = pos_abs & 1;
                    int slot = arr ? (pos_abs + 1) / 2 : pos_abs / 2 + 1;
                    base = ((((size_t)b * NGo + gq) * 2 + arr) * OSLOTS + slot) * 8;
                } else {
                    base = (((size_t)b * NGo + gq) * OSLOTS + (pos_abs + 1)) * 8;
                }
                *(short8*)(opl + base) = rh;
                *(short8*)(opl + PLOUT + base) = rm2;
                *(short8*)(opl + 2 * PLOUT + base) = rl2;
            }
        }
    }

    if (EPI == 0) {
        if (blockIdx.x == 0 && tid < 96) {
            int sg = tid / 32, r2 = tid % 32, g16 = r2 >> 1, a2 = r2 & 1;
            int gq = ob * 16 + g16;
            short8 z;
            #pragma unroll
            for (int j = 0; j < 8; ++j) z[j] = 0;
            *(short8*)(opl + (size_t)sg * PLOUT +
                       ((((size_t)b * NGo + gq) * 2 + a2) * OSLOTS) * 8) = z;
        }
    } else if (EPI == 1) {
        if (tid < 48 && (blockIdx.x == 0 || blockIdx.x == gridDim.x - 1)) {
            int sg = tid / 16, g16 = tid % 16;
            int gq = ob * 16 + g16;
            int slot = (blockIdx.x == 0) ? 0 : (OSLOTS - 1);
            short8 z;
            #pragma unroll
            for (int j = 0; j < 8; ++j) z[j] = 0;
            *(short8*)(opl + (size_t)sg * PLOUT +
                       (((size_t)b * NGo + gq) * OSLOTS + slot) * 8) = z;
        }
    }
}

// ---------- row split: src[N][128] fp32 -> 3 bf16 planes (fragment order) + sumsq
__global__ __launch_bounds__(256)
void split_kernel(const float* __restrict__ src, int nrows,
                  short* __restrict__ ph, short* __restrict__ pm,
                  short* __restrict__ pl, float* __restrict__ sumv)
{
    int t = blockIdx.x * 256 + threadIdx.x;
    int n = t >> 4, g = t & 15;
    if (n >= nrows) return;
    const float* rowp = src + (size_t)n * 128 + g * 8;
    float4 v0 = *(const float4*)rowp;
    float4 v1 = *(const float4*)(rowp + 4);
    float vv[8] = {v0.x, v0.y, v0.z, v0.w, v1.x, v1.y, v1.z, v1.w};
    short8 rh, rm, rl;
    float ss = 0.0f;
    #pragma unroll
    for (int j = 0; j < 8; ++j) {
        float v = vv[j];
        ss = fmaf(v, v, ss);
        unsigned short uh = f2bf(v);
        float r1 = v - bf2f(uh);
        unsigned short um = f2bf(r1);
        unsigned short ul = f2bf(r1 - bf2f(um));
        rh[j] = (short)uh; rm[j] = (short)um; rl[j] = (short)ul;
    }
    int nb = n >> 5, m = n & 31, ks = g >> 1, hi = g & 1;
    size_t slot = ((((size_t)nb * 8 + ks) * 2 + hi) * 32 + m) * 8;
    *(short8*)(ph + slot) = rh;
    *(short8*)(pm + slot) = rm;
    *(short8*)(pl + slot) = rl;
    #pragma unroll
    for (int mk = 8; mk; mk >>= 1) ss += __shfl_xor(ss, mk);
    if (g == 0) sumv[n] = ss;
}

// ---------- dist tile (128n x 128k): direct-from-global MFMA + fused argmin ----
// No staging LDS: split planes are stored in fragment order, so per-lane
// global_load_dwordx4 IS the fragment load (L2-resident operands, 9 MB total).
// LDS = 64KB argmin candidate table only -> 2 blocks/CU, 8 waves.
__global__ __launch_bounds__(256, 2)
void distmin_kernel(const short* __restrict__ fh, const short* __restrict__ fm,
                    const short* __restrict__ fl, const short* __restrict__ eh,
                    const short* __restrict__ em, const short* __restrict__ el,
                    const float* __restrict__ sf, const float* __restrict__ se,
                    float* __restrict__ dist, unsigned long long* __restrict__ mp)
{
    __shared__ unsigned long long cand[128 * 64];   // 64 KB
    const int tid = threadIdx.x;
    const int lane = tid & 63;
    const int wv = tid >> 6;
    const int wm = wv >> 1, wn = wv & 1;
    const int hi = lane >> 5, n32 = lane & 31;
    const int kb = blockIdx.x;   // 0..31  (k-tile of 128)
    const int nb = blockIdx.y;   // 0..63  (n-tile of 128)

    f32x16 acc[2][2];
    #pragma unroll
    for (int i = 0; i < 2; ++i)
        #pragma unroll
        for (int j = 0; j < 2; ++j)
            #pragma unroll
            for (int e = 0; e < 16; ++e) acc[i][j][e] = 0.0f;

    // per-lane fragment base pointers (shorts); per-ks stride = 512 shorts
    const short* fb[3][2];
    const short* eb[3][2];
    {
        const short* fpl[3] = {fh, fm, fl};
        const short* epl[3] = {eh, em, el};
        #pragma unroll
        for (int s = 0; s < 3; ++s) {
            #pragma unroll
            for (int mf = 0; mf < 2; ++mf)
                fb[s][mf] = fpl[s] + (size_t)nb * 16384
                            + ((size_t)(wm * 2 + mf) * 8 * 64 + lane) * 8;
            #pragma unroll
            for (int nf = 0; nf < 2; ++nf)
                eb[s][nf] = epl[s]
                            + ((size_t)(kb * 4 + wn * 2 + nf) * 8 * 64 + lane) * 8;
        }
    }

    #pragma unroll
    for (int ks = 0; ks < 8; ++ks) {
        short8 af[3][2], bx[3][2];
        #pragma unroll
        for (int s = 0; s < 3; ++s) {
            #pragma unroll
            for (int mf = 0; mf < 2; ++mf)
                af[s][mf] = *(const short8*)(fb[s][mf] + ks * 512);
            #pragma unroll
            for (int nf = 0; nf < 2; ++nf)
                bx[s][nf] = *(const short8*)(eb[s][nf] + ks * 512);
        }
        constexpr int PA[6] = {0, 0, 1, 1, 0, 2};
        constexpr int PB[6] = {0, 1, 0, 1, 2, 0};
        #pragma unroll
        for (int p = 0; p < 6; ++p)
            #pragma unroll
            for (int mf = 0; mf < 2; ++mf)
                #pragma unroll
                for (int nf = 0; nf < 2; ++nf)
                    acc[mf][nf] = __builtin_amdgcn_mfma_f32_32x32x16_bf16(
                        af[PA[p]][mf], bx[PB[p]][nf], acc[mf][nf], 0, 0, 0);
    }

    // epilogue: dist = (sf+se) - 2*dot ; write + per-row candidates
    const int n_blk = nb * 128;
    const int kc0 = kb * 128 + wn * 64 + n32;       // nf=0 column
    const float se0 = se[kc0];
    const float se1 = se[kc0 + 32];
    #pragma unroll
    for (int mf = 0; mf < 2; ++mf) {
        #pragma unroll
        for (int r = 0; r < 16; ++r) {
            int nloc = wm * 64 + mf * 32 + (r & 3) + 8 * (r >> 2) + 4 * hi;
            int n = n_blk + nloc;
            float sfn = sf[n];
            float v0 = (sfn + se0) - 2.0f * acc[mf][0][r];
            float v1 = (sfn + se1) - 2.0f * acc[mf][1][r];
            dist[(size_t)n * 4096 + kc0] = v0;
            dist[(size_t)n * 4096 + kc0 + 32] = v1;
            unsigned long long p0 =
                (((unsigned long long)__float_as_uint(v0)) << 32) | (unsigned)kc0;
            unsigned long long p1 =
                (((unsigned long long)__float_as_uint(v1)) << 32) | (unsigned)(kc0 + 32);
            unsigned long long p = p1 < p0 ? p1 : p0;
            cand[nloc * 64 + wn * 32 + n32] = p;
        }
    }
    __syncthreads();
    {
        int row = tid >> 1, h = tid & 1;
        unsigned long long best = ~0ULL;
        #pragma unroll
        for (int i = 0; i < 32; ++i) {
            int c = h * 32 + ((i + row) & 31);   // rotation: avoid bank degeneracy
            unsigned long long cv = cand[row * 64 + c];
            best = cv < best ? cv : best;
        }
        unsigned lo = (unsigned)best, hw = (unsigned)(best >> 32);
        unsigned lo2 = __shfl_xor(lo, 1), hw2 = __shfl_xor(hw, 1);
        unsigned long long ob = (((unsigned long long)hw2) << 32) | lo2;
        if (ob < best) best = ob;
        if (h == 0) atomicMin(mp + n_blk + row, best);
    }
}

// ---------- unpack codes ----------
__global__ __launch_bounds__(256)
void codes_kernel(const unsigned long long* __restrict__ mp,
                  float* __restrict__ codes)
{
    int n = blockIdx.x * 256 + threadIdx.x;
    if (n < 8192) codes[n] = (float)(unsigned)(mp[n] & 0xffffffffULL);
}

// ---------------------------------------------------------------
extern "C" void kernel_launch(void* const* d_in, const int* in_sizes, int n_in,
                              void* d_out, int out_size, void* d_ws, size_t ws_size,
                              hipStream_t stream)
{
    const float* x   = (const float*)d_in[0];
    const float* w1  = (const float*)d_in[1];
    const float* b1  = (const float*)d_in[2];
    const float* w2  = (const float*)d_in[3];
    const float* b2  = (const float*)d_in[4];
    const float* w3  = (const float*)d_in[5];
    const float* b3  = (const float*)d_in[6];
    const float* w4  = (const float*)d_in[7];
    const float* b4  = (const float*)d_in[8];
    const float* g1  = (const float*)d_in[9];
    const float* be1 = (const float*)d_in[10];
    const float* m1  = (const float*)d_in[11];
    const float* v1  = (const float*)d_in[12];
    const float* g2  = (const float*)d_in[13];
    const float* be2 = (const float*)d_in[14];
    const float* m2  = (const float*)d_in[15];
    const float* v2  = (const float*)d_in[16];
    const float* g3  = (const float*)d_in[17];
    const float* be3 = (const float*)d_in[18];
    const float* m3  = (const float*)d_in[19];
    const float* v3  = (const float*)d_in[20];
    const float* g4  = (const float*)d_in[21];
    const float* be4 = (const float*)d_in[22];
    const float* m4  = (const float*)d_in[23];
    const float* v4  = (const float*)d_in[24];
    const float* emb = (const float*)d_in[25];

    float* outf  = (float*)d_out;
    float* codes = outf;
    float* distm = outf + 8192;

    // ---- workspace layout (bytes)
    char* wsb = (char*)d_ws;
    short* wb1 = (short*)(wsb + 0);
    short* wb2 = (short*)(wsb + 1179648);
    short* wb3 = (short*)(wsb + 3538944);
    short* wb4 = (short*)(wsb + 8257536);
    float* sc1 = (float*)(wsb + 9437184); float* off1 = sc1 + 256;
    float* sc2 = (float*)(wsb + 9439232); float* off2 = sc2 + 512;
    float* sc3 = (float*)(wsb + 9443328); float* off3 = sc3 + 512;
    float* sc4 = (float*)(wsb + 9447424); float* off4 = sc4 + 128;
    short* h1p = (short*)(wsb + 9449472);        // 50,429,952
    short* fh  = (short*)(wsb + 59879424);       // 2,097,152 each
    short* fm  = (short*)(wsb + 61976576);
    short* fl  = (short*)(wsb + 64073728);
    short* eh  = (short*)(wsb + 66170880);       // 1,048,576 each
    short* em  = (short*)(wsb + 67219456);
    short* el  = (short*)(wsb + 68268032);
    float* sf  = (float*)(wsb + 69316608);
    float* se  = (float*)(wsb + 69349376);
    unsigned long long* mp = (unsigned long long*)(wsb + 69365760);  // 65,536

    // ---- large scratch in the (dead-until-dist) dist region of d_out
    char* db = (char*)distm;
    short* xpl = (short*)db;                      // L1 input planes
    short* h2p = (short*)db;                      // L2 output planes
    short* h3p = (short*)(db + 50528256);         // L3 output planes
    float* f   = (float*)(db + 80000000);         // fp32 features [8192][128]

    // ---- prep
    wprep_mfma<<<288,  256, 0, stream>>>(w1, wb1, 256, 256);
    wprep_mfma<<<576,  256, 0, stream>>>(w2, wb2, 256, 512);
    wprep_mfma<<<1152, 256, 0, stream>>>(w3, wb3, 512, 512);
    wprep_mfma<<<288,  256, 0, stream>>>(w4, wb4, 512, 128);
    bnprep<<<4, 64, 0, stream>>>(g1, be1, m1, v1, b1, sc1, off1, 256);
    bnprep<<<8, 64, 0, stream>>>(g2, be2, m2, v2, b2, sc2, off2, 512);
    bnprep<<<8, 64, 0, stream>>>(g3, be3, m3, v3, b3, sc3, off3, 512);
    bnprep<<<2, 64, 0, stream>>>(g4, be4, m4, v4, b4, sc4, off4, 128);
    hipMemsetAsync(mp, 0xFF, 8192 * 8, stream);
    split_kernel<<<256, 256, 0, stream>>>(emb, 4096, eh, em, el, se);

    // ---- input split + conv stack
    xsplit<<<dim3(8, 32, 32), 256, 0, stream>>>(x, xpl);
    conv_mfma<256, 256, 2048, 2, 0>
        <<<dim3(8, 2, 32), 256, 0, stream>>>(wb1, xpl, sc1, off1, h1p, nullptr);
    conv_mfma<256, 512, 1024, 2, 0>
        <<<dim3(4, 4, 32), 256, 0, stream>>>(wb2, h1p, sc2, off2, h2p, nullptr);
    conv_mfma<512, 512, 512, 2, 1>
        <<<dim3(2, 4, 32), 256, 0, stream>>>(wb3, h2p, sc3, off3, h3p, nullptr);
    conv_mfma<512, 128, 256, 1, 2>
        <<<dim3(2, 1, 32), 256, 0, stream>>>(wb4, h3p, sc4, off4, nullptr, f);

    // ---- VQ: split f, MFMA distance + fused argmin, unpack codes
    split_kernel<<<512, 256, 0, stream>>>(f, 8192, fh, fm, fl, sf);
    distmin_kernel<<<dim3(32, 64), 256, 0, stream>>>(fh, fm, fl, eh, em, el,
                                                     sf, se, distm, mp);
    codes_kernel<<<32, 256, 0, stream>>>(mp, codes);
}